// Round 7
// baseline (52.760 us; speedup 1.0000x reference)
//
#include <hip/hip_runtime.h>

// PatchManifoldLossPre: resize (8,19,512,512) -> (8,19,48,48) with jax.image.resize
// bilinear (antialias=True, triangle kernel, half-pixel centers), split into 4x4
// patches of 12x12, P[16, 21888], value = mean(weights * pairwise-MSD(P)).
// pairwise-MSD via Gram: map[a,b] = (G[aa]+G[bb]-2G[ab])/N.
//
// Round-7: reduce load amplification 2.06x -> 1.59x: each thread produces TWO
// adjacent output rows from ONE 34-row load stream (pair union window <= 34,
// zero-padded, clamped so the fixed unrolled loop is always in-bounds).
// Weights/starts are compile-time __constant__ tables; pair index is
// wave-uniform so weight reads are s_load (scalar) — no LDS, no preamble.
// 1824 blocks (152 bc x 12 quads, = 8*228 XCD-chunked) x 256 threads.

#define HIN 512
#define WOUT 48
#define NTAP 22
#define NBC 152              // 8*19
#define NQUAD 12             // quads of 4 output rows per bc
#define NBLK (NBC * NQUAD)   // 1824 = 8 * 228
#define PSPAN 34             // padded union window for an output-row pair
#define TSTRIDE 580          // swizzled LDS row stride in floats
#define GROUP 12             // patch size
#define KS (512.0 / 48.0)

// Compile-time triangle-kernel resize weights matching jax.image.resize
// (method="bilinear", antialias=True): sample s=(i+0.5)*KS-0.5, kernel scale KS,
// normalized over valid taps. Per-output window clamped into [0, HIN-NTAP].
// Pair tables: for pair p (outputs 2p, 2p+1), start[p] = clamp(hst[2p], 0, 478)
// and w[p][row][r] = weight of input row start[p]+row in output 2p+r (0 outside
// that output's 22-tap window) — fixed 34-iteration branchless vertical loop.
struct PTab {
  float hw[NTAP][WOUT];
  int hst[WOUT];
  float pw[24][PSPAN][2];
  int pstart[24];
  constexpr PTab() : hw{}, hst{}, pw{}, pstart{} {
    double wfull[WOUT][NTAP] = {};
    for (int i = 0; i < WOUT; ++i) {
      double s = (i + 0.5) * KS - 0.5;
      double v = s - KS;
      long long tt = (long long)v;
      int stc = (int)((v > (double)tt) ? tt + 1 : tt);  // ceil(v)
      if (stc < 0) stc = 0;
      if (stc > HIN - NTAP) stc = HIN - NTAP;
      double sum = 0.0;
      for (int k = 0; k < NTAP; ++k) {
        int j = stc + k;
        double d = s - (double)j;
        if (d < 0) d = -d;
        double wv = 1.0 - d * (1.0 / KS);
        if (wv < 0.0) wv = 0.0;
        if (j >= HIN) wv = 0.0;
        wfull[i][k] = wv;
        sum += wv;
      }
      for (int k = 0; k < NTAP; ++k) {
        wfull[i][k] /= sum;
        hw[k][i] = (float)wfull[i][k];
      }
      hst[i] = stc;
    }
    for (int p = 0; p < 24; ++p) {
      int lo = hst[2 * p];
      if (lo > HIN - PSPAN) lo = HIN - PSPAN;
      pstart[p] = lo;
      for (int row = 0; row < PSPAN; ++row) {
        for (int r = 0; r < 2; ++r) {
          int oy = 2 * p + r;
          int k = lo + row - hst[oy];
          pw[p][row][r] =
              (k >= 0 && k < NTAP) ? (float)wfull[oy][k] : 0.f;
        }
      }
    }
  }
};
__constant__ PTab PT{};

__global__ __launch_bounds__(256, 6) void k_resize(const float* __restrict__ pred,
                                                   float* __restrict__ smallimg,
                                                   float* __restrict__ G,
                                                   unsigned* __restrict__ ticket) {
  __shared__ float tile[4][TSTRIDE];  // 9280 B, swizzled (c -> c + 4*(c>>5))

  const int t = threadIdx.x;
  // XCD-chunked remap (bijective: 1824 = 8*228): round-robin XCD assignment gets
  // contiguous work chunks so window-overlapping quads reuse that XCD's L2.
  const int wid = (blockIdx.x & 7) * (NBLK / 8) + (blockIdx.x >> 3);
  const int bc = wid / NQUAD;
  const int q = wid - bc * NQUAD;

  // Replace the memset dispatch: visible to k_gram_final at kernel boundary.
  if (blockIdx.x == 0) {
    G[t] = 0.f;
    if (t == 0) *ticket = 0u;
  }

  // ---- Vertical pass: thread = (pair slot, float4 slice); 2 output rows from
  // one 34-row stream. Weight reads are wave-uniform -> scalar loads. ----
  const int slot = t >> 7;            // 0..1 (wave-uniform)
  const int p = q * 2 + slot;         // pair index 0..23
  const int x = (t & 127) << 2;       // 0..508
  const int lo = PT.pstart[p];
  const float* src = pred + (size_t)bc * (HIN * HIN) + (size_t)lo * HIN + x;
  float4 a0 = make_float4(0.f, 0.f, 0.f, 0.f);
  float4 a1 = make_float4(0.f, 0.f, 0.f, 0.f);
#pragma unroll
  for (int row = 0; row < PSPAN; ++row) {
    const float4 v = *reinterpret_cast<const float4*>(src + (size_t)row * HIN);
    const float w0 = PT.pw[p][row][0];
    const float w1 = PT.pw[p][row][1];
    a0.x = fmaf(w0, v.x, a0.x); a0.y = fmaf(w0, v.y, a0.y);
    a0.z = fmaf(w0, v.z, a0.z); a0.w = fmaf(w0, v.w, a0.w);
    a1.x = fmaf(w1, v.x, a1.x); a1.y = fmaf(w1, v.y, a1.y);
    a1.z = fmaf(w1, v.z, a1.z); a1.w = fmaf(w1, v.w, a1.w);
  }
  const int xph = x + ((x >> 5) << 2);
  *reinterpret_cast<float4*>(&tile[slot * 2 + 0][xph]) = a0;
  *reinterpret_cast<float4*>(&tile[slot * 2 + 1][xph]) = a1;
  __syncthreads();

  // ---- Horizontal gather (192 of 256 threads) -> smallimg ----
  if (t < 4 * WOUT) {
    const int r = t / WOUT;           // 0..3
    const int j = t - r * WOUT;
    const int stc = PT.hst[j];
    float acc = 0.f;
#pragma unroll
    for (int k = 0; k < NTAP; ++k) {
      const int cc = stc + k;
      acc = fmaf(PT.hw[k][j], tile[r][cc + ((cc >> 5) << 2)], acc);
    }
    smallimg[(size_t)bc * (WOUT * WOUT) + (q * 4 + r) * WOUT + j] = acc;
  }
}

// One block per (b,c): stage 48x48 image in LDS, thread owns pair (a,b), Gram via
// atomics into G; the LAST block (device-scope ticket) computes the final scalar.
__global__ __launch_bounds__(256) void k_gram_final(const float* __restrict__ smallimg,
                                                    const float* __restrict__ wts,
                                                    float* __restrict__ G,
                                                    unsigned* __restrict__ ticket,
                                                    float* __restrict__ out) {
  __shared__ float img[WOUT * WOUT];
  __shared__ float Gs[256];
  __shared__ float partial[4];
  __shared__ unsigned lastv;

  const int tid = threadIdx.x;
  const float* src = smallimg + (size_t)blockIdx.x * (WOUT * WOUT);
  for (int idx = tid; idx < (WOUT * WOUT) / 4; idx += 256) {
    *reinterpret_cast<float4*>(&img[idx * 4]) =
        *reinterpret_cast<const float4*>(src + idx * 4);
  }
  __syncthreads();
  const int a = tid >> 4;
  const int b = tid & 15;
  const float* pa = &img[((a >> 2) * GROUP) * WOUT + (a & 3) * GROUP];
  const float* pb = &img[((b >> 2) * GROUP) * WOUT + (b & 3) * GROUP];
  float acc = 0.f;
  for (int y = 0; y < GROUP; ++y) {
#pragma unroll
    for (int qq = 0; qq < 3; ++qq) {
      const float4 va = *reinterpret_cast<const float4*>(pa + y * WOUT + qq * 4);
      const float4 vb = *reinterpret_cast<const float4*>(pb + y * WOUT + qq * 4);
      acc += va.x * vb.x + va.y * vb.y + va.z * vb.z + va.w * vb.w;
    }
  }
  atomicAdd(&G[tid], acc);
  __threadfence();   // release: G-atomics ordered before the ticket increment
  __syncthreads();   // all 256 lanes' atomics issued+fenced before tid 0 tickets
  if (tid == 0) lastv = atomicAdd(ticket, 1u);
  __syncthreads();
  if (lastv != NBC - 1) return;

  // Last block: coherent readback of G (device-scope atomic read), then reduce.
  __threadfence();
  Gs[tid] = atomicAdd(&G[tid], 0.f);
  __syncthreads();
  float v = wts[tid] * (Gs[a * 17] + Gs[b * 17] - 2.0f * Gs[tid]);
#pragma unroll
  for (int off = 32; off > 0; off >>= 1) v += __shfl_down(v, off, 64);
  if ((tid & 63) == 0) partial[tid >> 6] = v;
  __syncthreads();
  if (tid == 0) {
    out[0] = (partial[0] + partial[1] + partial[2] + partial[3]) *
             (float)(1.0 / (256.0 * 21888.0));
  }
}

extern "C" void kernel_launch(void* const* d_in, const int* in_sizes, int n_in,
                              void* d_out, int out_size, void* d_ws, size_t ws_size,
                              hipStream_t stream) {
  const float* pred = (const float*)d_in[0];
  const float* wts = (const float*)d_in[1];
  float* out = (float*)d_out;
  float* G = (float*)d_ws;                              // bytes [0, 1024)
  unsigned* ticket = (unsigned*)((char*)d_ws + 1024);   // bytes [1024, 1028)
  float* smallimg = (float*)((char*)d_ws + 2048);       // 152*48*48 floats

  hipLaunchKernelGGL(k_resize, dim3(NBLK), dim3(256), 0, stream,
                     pred, smallimg, G, ticket);
  hipLaunchKernelGGL(k_gram_final, dim3(NBC), dim3(256), 0, stream,
                     smallimg, wts, G, ticket, out);
}

// Round 8
// 37.537 us; speedup vs baseline: 1.4055x; 1.4055x over previous
//
#include <hip/hip_runtime.h>

// PatchManifoldLossPre: resize (8,19,512,512) -> (8,19,48,48) with jax.image.resize
// bilinear (antialias=True, triangle kernel, half-pixel centers), split into 4x4
// patches of 12x12, P[16, 21888], value = mean(weights * pairwise-MSD(P)).
// pairwise-MSD via Gram: map[a,b] = (G[aa]+G[bb]-2G[ab])/N.
//
// Round-8: best resize (r5: 3648 blocks x 256, 1 output row per thread-slot,
// 22 independent coalesced loads, swizzled-LDS horizontal gather, constexpr
// weight tables) + DE-TICKETED tail: plain-atomic k_gram and 1-block k_final
// (r2-validated kernel-boundary visibility). Tests the hypothesis that the
// ticket/threadfence/atomic-readback pattern was costing ~8 us (r2 vs r3).

#define HIN 512
#define WOUT 48
#define NTAP 22
#define NBC 152              // 8*19
#define NPAIR 24             // row-pairs per bc
#define NBLK (NBC * NPAIR)   // 3648 = 8 * 456
#define TSTRIDE 580          // swizzled LDS row stride in floats
#define GROUP 12             // patch size
#define KS (512.0 / 48.0)

// Compile-time triangle-kernel resize weights matching jax.image.resize
// (method="bilinear", antialias=True): sample s=(i+0.5)*KS-0.5, kernel scale KS,
// normalized over valid taps. Window clamped into [0, HIN-NTAP].
struct WTab {
  float hw[NTAP][WOUT];
  int hst[WOUT];
  constexpr WTab() : hw{}, hst{} {
    for (int i = 0; i < WOUT; ++i) {
      double s = (i + 0.5) * KS - 0.5;
      double v = s - KS;
      long long tt = (long long)v;                      // trunc toward zero
      int stc = (int)((v > (double)tt) ? tt + 1 : tt);  // ceil(v)
      if (stc < 0) stc = 0;
      if (stc > HIN - NTAP) stc = HIN - NTAP;
      double wr[NTAP] = {};
      double sum = 0.0;
      for (int k = 0; k < NTAP; ++k) {
        int j = stc + k;
        double d = s - (double)j;
        if (d < 0) d = -d;
        double wv = 1.0 - d * (1.0 / KS);
        if (wv < 0.0) wv = 0.0;
        if (j >= HIN) wv = 0.0;  // j<0 impossible after clamp
        wr[k] = wv;
        sum += wv;
      }
      for (int k = 0; k < NTAP; ++k) hw[k][i] = (float)(wr[k] / sum);
      hst[i] = stc;
    }
  }
};
__constant__ WTab WT{};

__global__ __launch_bounds__(256, 6) void k_resize(const float* __restrict__ pred,
                                                   float* __restrict__ smallimg,
                                                   float* __restrict__ G) {
  __shared__ float tile[2][TSTRIDE];  // 4640 B, swizzled (c -> c + 4*(c>>5))

  const int t = threadIdx.x;
  // XCD-chunked remap (bijective: 3648 = 8*456): round-robin XCD assignment gets
  // contiguous work chunks so row-adjacent pairs reuse that XCD's L2 tap rows.
  const int wid = (blockIdx.x & 7) * (NBLK / 8) + (blockIdx.x >> 3);
  const int bc = wid / NPAIR;
  const int pair = wid - bc * NPAIR;

  // Replace the memset dispatch: visible to k_gram at the kernel boundary.
  if (blockIdx.x == 0) G[t] = 0.f;

  // ---- Vertical pass: thread = (output row slot, float4 column slice) ----
  const int slot = t >> 7;              // 0..1 (wave-uniform)
  const int oy = pair * 2 + slot;
  const int x = (t & 127) << 2;         // 0..508
  const int base = WT.hst[oy];
  const float* p = pred + (size_t)bc * (HIN * HIN) + (size_t)base * HIN + x;
  float4 a = make_float4(0.f, 0.f, 0.f, 0.f);
#pragma unroll
  for (int k = 0; k < NTAP; ++k) {
    const float4 v = *reinterpret_cast<const float4*>(p + (size_t)k * HIN);
    const float wk = WT.hw[k][oy];      // wave-uniform constant read -> s_load
    a.x = fmaf(wk, v.x, a.x);
    a.y = fmaf(wk, v.y, a.y);
    a.z = fmaf(wk, v.z, a.z);
    a.w = fmaf(wk, v.w, a.w);
  }
  *reinterpret_cast<float4*>(&tile[slot][x + ((x >> 5) << 2)]) = a;
  __syncthreads();

  // ---- Horizontal gather (96 of 256 threads) -> smallimg ----
  if (t < 2 * WOUT) {
    const int r = (t >= WOUT) ? 1 : 0;
    const int j = t - r * WOUT;
    const int stc = WT.hst[j];
    float acc = 0.f;
#pragma unroll
    for (int k = 0; k < NTAP; ++k) {
      const int cc = stc + k;
      acc = fmaf(WT.hw[k][j], tile[r][cc + ((cc >> 5) << 2)], acc);
    }
    smallimg[(size_t)bc * (WOUT * WOUT) + (pair * 2 + r) * WOUT + j] = acc;
  }
}

// One block per (b,c): stage 48x48 image in LDS, thread owns pair (a,b),
// Gram accumulated via device-scope atomics (coherent; no fence needed —
// k_final reads after the kernel boundary). r2-validated pattern.
__global__ __launch_bounds__(256) void k_gram(const float* __restrict__ smallimg,
                                              float* __restrict__ G) {
  __shared__ float img[WOUT * WOUT];
  const int tid = threadIdx.x;
  const float* src = smallimg + (size_t)blockIdx.x * (WOUT * WOUT);
  for (int idx = tid; idx < (WOUT * WOUT) / 4; idx += 256) {
    *reinterpret_cast<float4*>(&img[idx * 4]) =
        *reinterpret_cast<const float4*>(src + idx * 4);
  }
  __syncthreads();
  const int a = tid >> 4;
  const int b = tid & 15;
  const float* pa = &img[((a >> 2) * GROUP) * WOUT + (a & 3) * GROUP];
  const float* pb = &img[((b >> 2) * GROUP) * WOUT + (b & 3) * GROUP];
  float acc = 0.f;
  for (int y = 0; y < GROUP; ++y) {
#pragma unroll
    for (int q = 0; q < 3; ++q) {
      const float4 va = *reinterpret_cast<const float4*>(pa + y * WOUT + q * 4);
      const float4 vb = *reinterpret_cast<const float4*>(pb + y * WOUT + q * 4);
      acc += va.x * vb.x + va.y * vb.y + va.z * vb.z + va.w * vb.w;
    }
  }
  atomicAdd(&G[tid], acc);
}

// value = sum_{a,b} w[a,b]*(G[aa]+G[bb]-2G[ab]) / (256*N),  N = 152*144
__global__ __launch_bounds__(256) void k_final(const float* __restrict__ G,
                                               const float* __restrict__ wts,
                                               float* __restrict__ out) {
  __shared__ float partial[4];
  const int tid = threadIdx.x;
  const int a = tid >> 4;
  const int b = tid & 15;
  float v = wts[tid] * (G[a * 17] + G[b * 17] - 2.0f * G[tid]);
#pragma unroll
  for (int off = 32; off > 0; off >>= 1) v += __shfl_down(v, off, 64);
  if ((tid & 63) == 0) partial[tid >> 6] = v;
  __syncthreads();
  if (tid == 0) {
    out[0] = (partial[0] + partial[1] + partial[2] + partial[3]) *
             (float)(1.0 / (256.0 * 21888.0));
  }
}

extern "C" void kernel_launch(void* const* d_in, const int* in_sizes, int n_in,
                              void* d_out, int out_size, void* d_ws, size_t ws_size,
                              hipStream_t stream) {
  const float* pred = (const float*)d_in[0];
  const float* wts = (const float*)d_in[1];
  float* out = (float*)d_out;
  float* G = (float*)d_ws;                         // 256 floats
  float* smallimg = (float*)((char*)d_ws + 2048);  // 152*48*48 floats

  hipLaunchKernelGGL(k_resize, dim3(NBLK), dim3(256), 0, stream, pred, smallimg, G);
  hipLaunchKernelGGL(k_gram, dim3(NBC), dim3(256), 0, stream, smallimg, G);
  hipLaunchKernelGGL(k_final, dim3(1), dim3(256), 0, stream, G, wts, out);
}

// Round 9
// 34.884 us; speedup vs baseline: 1.5125x; 1.0761x over previous
//
#include <hip/hip_runtime.h>

// PatchManifoldLossPre: resize (8,19,512,512) -> (8,19,48,48) with jax.image.resize
// bilinear (antialias=True, triangle kernel, half-pixel centers), split into 4x4
// patches of 12x12, P[16, 21888], value = mean(weights * pairwise-MSD(P)).
// pairwise-MSD via Gram: map[a,b] = (G[aa]+G[bb]-2G[ab])/N.
//
// Round-9: 2 dispatches, no global Gram. The final value is LINEAR in the
// per-bc Gram, so each k_gram block computes its local 16x16 Gram in LDS,
// applies the weight reduction locally, and atomicAdds ONE pre-scaled float
// into out[0] (zeroed by k_resize block 0). Deletes k_final, one launch gap,
// the G buffer, and all wide global atomics. k_resize = r5/r8 measured best:
// 3648 blocks x 256, 1 output row per thread-slot, 22 independent coalesced
// float4 loads, constexpr weight tables, swizzled-LDS horizontal gather.

#define HIN 512
#define WOUT 48
#define NTAP 22
#define NBC 152              // 8*19
#define NPAIR 24             // row-pairs per bc
#define NBLK (NBC * NPAIR)   // 3648 = 8 * 456
#define TSTRIDE 580          // swizzled LDS row stride in floats
#define GROUP 12             // patch size
#define KS (512.0 / 48.0)

// Compile-time triangle-kernel resize weights matching jax.image.resize
// (method="bilinear", antialias=True): sample s=(i+0.5)*KS-0.5, kernel scale KS,
// normalized over valid taps. Window clamped into [0, HIN-NTAP].
struct WTab {
  float hw[NTAP][WOUT];
  int hst[WOUT];
  constexpr WTab() : hw{}, hst{} {
    for (int i = 0; i < WOUT; ++i) {
      double s = (i + 0.5) * KS - 0.5;
      double v = s - KS;
      long long tt = (long long)v;                      // trunc toward zero
      int stc = (int)((v > (double)tt) ? tt + 1 : tt);  // ceil(v)
      if (stc < 0) stc = 0;
      if (stc > HIN - NTAP) stc = HIN - NTAP;
      double wr[NTAP] = {};
      double sum = 0.0;
      for (int k = 0; k < NTAP; ++k) {
        int j = stc + k;
        double d = s - (double)j;
        if (d < 0) d = -d;
        double wv = 1.0 - d * (1.0 / KS);
        if (wv < 0.0) wv = 0.0;
        if (j >= HIN) wv = 0.0;  // j<0 impossible after clamp
        wr[k] = wv;
        sum += wv;
      }
      for (int k = 0; k < NTAP; ++k) hw[k][i] = (float)(wr[k] / sum);
      hst[i] = stc;
    }
  }
};
__constant__ WTab WT{};

__global__ __launch_bounds__(256, 6) void k_resize(const float* __restrict__ pred,
                                                   float* __restrict__ smallimg,
                                                   float* __restrict__ out) {
  __shared__ float tile[2][TSTRIDE];  // 4640 B, swizzled (c -> c + 4*(c>>5))

  const int t = threadIdx.x;
  // XCD-chunked remap (bijective: 3648 = 8*456): round-robin XCD assignment gets
  // contiguous work chunks so row-adjacent pairs reuse that XCD's L2 tap rows.
  const int wid = (blockIdx.x & 7) * (NBLK / 8) + (blockIdx.x >> 3);
  const int bc = wid / NPAIR;
  const int pair = wid - bc * NPAIR;

  // Zero the output accumulator (poisoned by harness): visible to k_gram at the
  // kernel boundary on the same stream.
  if (blockIdx.x == 0 && t == 0) out[0] = 0.f;

  // ---- Vertical pass: thread = (output row slot, float4 column slice) ----
  const int slot = t >> 7;              // 0..1 (wave-uniform)
  const int oy = pair * 2 + slot;
  const int x = (t & 127) << 2;         // 0..508
  const int base = WT.hst[oy];
  const float* p = pred + (size_t)bc * (HIN * HIN) + (size_t)base * HIN + x;
  float4 a = make_float4(0.f, 0.f, 0.f, 0.f);
#pragma unroll
  for (int k = 0; k < NTAP; ++k) {
    const float4 v = *reinterpret_cast<const float4*>(p + (size_t)k * HIN);
    const float wk = WT.hw[k][oy];      // wave-uniform constant read -> s_load
    a.x = fmaf(wk, v.x, a.x);
    a.y = fmaf(wk, v.y, a.y);
    a.z = fmaf(wk, v.z, a.z);
    a.w = fmaf(wk, v.w, a.w);
  }
  *reinterpret_cast<float4*>(&tile[slot][x + ((x >> 5) << 2)]) = a;
  __syncthreads();

  // ---- Horizontal gather (96 of 256 threads) -> smallimg ----
  if (t < 2 * WOUT) {
    const int r = (t >= WOUT) ? 1 : 0;
    const int j = t - r * WOUT;
    const int stc = WT.hst[j];
    float acc = 0.f;
#pragma unroll
    for (int k = 0; k < NTAP; ++k) {
      const int cc = stc + k;
      acc = fmaf(WT.hw[k][j], tile[r][cc + ((cc >> 5) << 2)], acc);
    }
    smallimg[(size_t)bc * (WOUT * WOUT) + (pair * 2 + r) * WOUT + j] = acc;
  }
}

// One block per (b,c): stage 48x48 image in LDS; thread (a,b)=(tid>>4,tid&15)
// computes local Gram entry; block applies the weight reduction LOCALLY
// (value is linear in per-bc Gram) and atomicAdds one pre-scaled float to out.
__global__ __launch_bounds__(256) void k_gram(const float* __restrict__ smallimg,
                                              const float* __restrict__ wts,
                                              float* __restrict__ out) {
  __shared__ float img[WOUT * WOUT];
  __shared__ float Gs[256];
  __shared__ float partial[4];

  const int tid = threadIdx.x;
  const float* src = smallimg + (size_t)blockIdx.x * (WOUT * WOUT);
  for (int idx = tid; idx < (WOUT * WOUT) / 4; idx += 256) {
    *reinterpret_cast<float4*>(&img[idx * 4]) =
        *reinterpret_cast<const float4*>(src + idx * 4);
  }
  __syncthreads();
  const int a = tid >> 4;
  const int b = tid & 15;
  const float* pa = &img[((a >> 2) * GROUP) * WOUT + (a & 3) * GROUP];
  const float* pb = &img[((b >> 2) * GROUP) * WOUT + (b & 3) * GROUP];
  float acc = 0.f;
  for (int y = 0; y < GROUP; ++y) {
#pragma unroll
    for (int q = 0; q < 3; ++q) {
      const float4 va = *reinterpret_cast<const float4*>(pa + y * WOUT + q * 4);
      const float4 vb = *reinterpret_cast<const float4*>(pb + y * WOUT + q * 4);
      acc += va.x * vb.x + va.y * vb.y + va.z * vb.z + va.w * vb.w;
    }
  }
  Gs[tid] = acc;
  __syncthreads();

  float v = wts[tid] * (Gs[a * 17] + Gs[b * 17] - 2.0f * Gs[tid]);
#pragma unroll
  for (int off = 32; off > 0; off >>= 1) v += __shfl_down(v, off, 64);
  if ((tid & 63) == 0) partial[tid >> 6] = v;
  __syncthreads();
  if (tid == 0) {
    atomicAdd(out, (partial[0] + partial[1] + partial[2] + partial[3]) *
                       (float)(1.0 / (256.0 * 21888.0)));
  }
}

extern "C" void kernel_launch(void* const* d_in, const int* in_sizes, int n_in,
                              void* d_out, int out_size, void* d_ws, size_t ws_size,
                              hipStream_t stream) {
  const float* pred = (const float*)d_in[0];
  const float* wts = (const float*)d_in[1];
  float* out = (float*)d_out;
  float* smallimg = (float*)((char*)d_ws + 2048);  // 152*48*48 floats

  hipLaunchKernelGGL(k_resize, dim3(NBLK), dim3(256), 0, stream, pred, smallimg, out);
  hipLaunchKernelGGL(k_gram, dim3(NBC), dim3(256), 0, stream, smallimg, wts, out);
}